// Round 9
// baseline (327.642 us; speedup 1.0000x reference)
//
#include <hip/hip_runtime.h>

typedef __attribute__((ext_vector_type(4))) float float4v;
typedef __attribute__((ext_vector_type(2))) float float2v;
typedef __attribute__((ext_vector_type(8))) short short8;
typedef __attribute__((ext_vector_type(4))) float f32x4;

#define NEGV (-1000000000.0f)

// B=64, L=2048, E=512, Q=256; M = 131072, K = 512, N = 512
#define MTOT (64 * 2048)

__device__ __forceinline__ unsigned short f2bf(float f) {
    unsigned int u = __float_as_uint(f);
    u += 0x7fffu + ((u >> 16) & 1u);   // RNE round to bf16
    return (unsigned short)(u >> 16);
}

// Wt[e][c] = bf16(W1[c][e]) via LDS 32x32 tile transpose (coalesced both sides).
__global__ __launch_bounds__(256)
void prep_wt_kernel(const float* __restrict__ W1, unsigned short* __restrict__ Wt) {
    __shared__ float t[32][33];
    int bx = blockIdx.x & 15;    // c tile
    int by = blockIdx.x >> 4;    // e tile
    int tx = threadIdx.x & 31;
    int ty = threadIdx.x >> 5;   // 0..7
    #pragma unroll
    for (int i = 0; i < 4; ++i)
        t[ty + 8 * i][tx] = W1[(bx * 32 + ty + 8 * i) * 512 + by * 32 + tx];
    __syncthreads();
    #pragma unroll
    for (int i = 0; i < 4; ++i)
        Wt[(by * 32 + ty + 8 * i) * 512 + bx * 32 + tx] = f2bf(t[tx][ty + 8 * i]);
}

// qc[b][e] = b1[e] + sum_q query[b][q] * W1[512+q][e]
__global__ void prep_qc_kernel(const float* __restrict__ query, const float* __restrict__ W1,
                               const float* __restrict__ b1, float* __restrict__ qc) {
    int b = blockIdx.x;
    int e = threadIdx.x;           // 256 threads -> cols e and e+256
    float acc0 = b1[e];
    float acc1 = b1[e + 256];
    const float* w = W1 + 512 * 512;
    #pragma unroll 8
    for (int q = 0; q < 256; ++q) {
        float qv = query[b * 256 + q];
        acc0 += qv * w[q * 512 + e];
        acc1 += qv * w[q * 512 + e + 256];
    }
    qc[b * 512 + e] = acc0;
    qc[b * 512 + e + 256] = acc1;
}

// Barrier-free wave-independent GEMM (R8 design; asm/pragma/launch-cap ghosts
// removed). Each wave owns a 64x64 output tile: A rows global->reg with
// plain-C f2bf packing (R1-verified), B cols global->reg (Wt L2-hot, 512KB),
// 16 MFMAs/K-step. No LDS, no s_barrier, no inter-wave coupling -> pure TLP
// latency hiding (R7 counters: barrier'd version was latency-bound at
// 8% MFMA / 5% HBM / 13% occupancy).
__global__ __launch_bounds__(256)
void gemm_logits_kernel(const float* __restrict__ A,            // encoded [M][512] f32
                        const unsigned short* __restrict__ Wt,  // [512 n][512 k] bf16
                        const float* __restrict__ qc,           // [64][512]
                        const float* __restrict__ v,            // [512]
                        const int* __restrict__ length,         // [64]
                        float* __restrict__ part)               // [8][M] partial logits
{
    // 4096 blocks: x = XCD, p = 64-row group (0..2047), h = col half.
    int bid = blockIdx.x;
    int x = bid & 7;
    int j = bid >> 3;              // 0..511
    int p = (j >> 1) * 8 + x;      // 0..2047 row group (64 rows)
    int h = j & 1;                 // 0..1
    int b = p >> 5;                // 32 row-groups per batch
    int l0 = (p & 31) * 64;
    if (l0 >= length[b]) return;   // fully-masked row group

    int lane = threadIdx.x & 63;
    int w = threadIdx.x >> 6;      // 0..3
    int cg = h * 4 + w;            // col group 0..7 (64 cols each)
    long row0 = (long)p * 64;
    int col0 = cg * 64;

    // fragment bases: lane l covers row (l&15)+16*mi, k-elems (l>>4)*8 ..+7
    const float* Abase = A + (row0 + (lane & 15)) * 512 + (lane >> 4) * 8;
    const unsigned short* Bbase = Wt + (long)(col0 + (lane & 15)) * 512 + (lane >> 4) * 8;

    f32x4 acc[4][4] = {};

    for (int k0 = 0; k0 < 512; k0 += 32) {
        short8 af[4], bf[4];
        #pragma unroll
        for (int mi = 0; mi < 4; ++mi) {
            const float* ap = Abase + mi * 16 * 512 + k0;
            float4v x0 = *(const float4v*)(ap);
            float4v x1 = *(const float4v*)(ap + 4);
            union { unsigned int u[4]; short8 s; } pk;
            pk.u[0] = (unsigned int)f2bf(x0[0]) | ((unsigned int)f2bf(x0[1]) << 16);
            pk.u[1] = (unsigned int)f2bf(x0[2]) | ((unsigned int)f2bf(x0[3]) << 16);
            pk.u[2] = (unsigned int)f2bf(x1[0]) | ((unsigned int)f2bf(x1[1]) << 16);
            pk.u[3] = (unsigned int)f2bf(x1[2]) | ((unsigned int)f2bf(x1[3]) << 16);
            af[mi] = pk.s;
        }
        #pragma unroll
        for (int ni = 0; ni < 4; ++ni)
            bf[ni] = *(const short8*)(Bbase + ni * 16 * 512 + k0);
        #pragma unroll
        for (int mi = 0; mi < 4; ++mi)
            #pragma unroll
            for (int ni = 0; ni < 4; ++ni)
                acc[mi][ni] = __builtin_amdgcn_mfma_f32_16x16x32_bf16(af[mi], bf[ni], acc[mi][ni], 0, 0, 0);
    }

    // epilogue: u = tanh(acc + qc), partial logit = sum over this wave's 64
    // cols of u*v, 16-lane reduce, store into slice cg (unique writer).
    const float* qcb = qc + b * 512;
    float vcol[4], qcol[4];
    #pragma unroll
    for (int ni = 0; ni < 4; ++ni) {
        int c = col0 + ni * 16 + (lane & 15);
        vcol[ni] = v[c];
        qcol[ni] = qcb[c];
    }
    float* pslice = part + cg * MTOT + row0;
    #pragma unroll
    for (int mi = 0; mi < 4; ++mi) {
        #pragma unroll
        for (int j2 = 0; j2 < 4; ++j2) {
            float s = 0.f;
            #pragma unroll
            for (int ni = 0; ni < 4; ++ni) {
                float xx = acc[mi][ni][j2] + qcol[ni];
                float e2 = __expf(2.0f * xx);
                float tt = 1.0f - 2.0f * __builtin_amdgcn_rcpf(e2 + 1.0f);
                s += tt * vcol[ni];
            }
            s += __shfl_xor(s, 1);
            s += __shfl_xor(s, 2);
            s += __shfl_xor(s, 4);
            s += __shfl_xor(s, 8);
            if ((lane & 15) == 0)
                pslice[mi * 16 + 4 * (lane >> 4) + j2] = s;
        }
    }
}

// masked softmax per batch row; sums 8 col-group partials; also zeroes ctx[b]
__global__ void softmax_kernel(const float* __restrict__ part, const int* __restrict__ length,
                               float* __restrict__ att, float* __restrict__ ctx) {
    int b = blockIdx.x;
    int len = length[b];
    int tid = threadIdx.x;     // 256
    int lane = tid & 63, wv = tid >> 6;
    const float* p0 = part + b * 2048;
    float* ab = att + b * 2048;

    ctx[b * 512 + tid] = 0.f;              // zero context (ctx_kernel atomicAdds)
    ctx[b * 512 + 256 + tid] = 0.f;

    float vals[8];
    float mymax = -3.402823466e38f;
    #pragma unroll
    for (int i = 0; i < 8; ++i) {
        int l = tid + i * 256;
        float xv = NEGV;
        if (l < len) {
            xv = 0.f;
            #pragma unroll
            for (int s = 0; s < 8; ++s)
                xv += p0[s * MTOT + l];
        }
        vals[i] = xv;
        mymax = fmaxf(mymax, xv);
    }
    #pragma unroll
    for (int m = 32; m; m >>= 1) mymax = fmaxf(mymax, __shfl_xor(mymax, m));
    __shared__ float sm[4];
    if (lane == 0) sm[wv] = mymax;
    __syncthreads();
    float bmax = fmaxf(fmaxf(sm[0], sm[1]), fmaxf(sm[2], sm[3]));

    float mysum = 0.f;
    #pragma unroll
    for (int i = 0; i < 8; ++i) {
        int l = tid + i * 256;
        float e = (l < len) ? __expf(vals[i] - bmax) : 0.f;
        vals[i] = e;
        mysum += e;
    }
    #pragma unroll
    for (int m = 32; m; m >>= 1) mysum += __shfl_xor(mysum, m);
    __shared__ float ss[4];
    if (lane == 0) ss[wv] = mysum;
    __syncthreads();
    float tot = ss[0] + ss[1] + ss[2] + ss[3];
    float inv = 1.0f / (tot + 1e-5f);
    #pragma unroll
    for (int i = 0; i < 8; ++i) {
        int l = tid + i * 256;
        ab[l] = vals[i] * inv;
    }
}

// context[b][e] = sum_l att[b][l] * enc[b][l][e]; skip masked L-chunks
__global__ void ctx_kernel(const float* __restrict__ att, const float* __restrict__ enc,
                           const int* __restrict__ length, float* __restrict__ ctx) {
    int b = blockIdx.x;        // 64
    int lc = blockIdx.y;       // 16 chunks of 128
    int len = length[b];
    int l0 = lc * 128;
    if (l0 >= len) return;
    int lim = len - l0;
    if (lim > 128) lim = 128;

    int t = threadIdx.x;       // 256 -> 2 cols each
    const float* ab = att + b * 2048 + l0;
    const float* eb = enc + ((long)(b * 2048 + l0)) * 512 + t * 2;
    float c0 = 0.f, c1 = 0.f;
    #pragma unroll 4
    for (int l = 0; l < lim; ++l) {
        float a = ab[l];
        float2v e = *(const float2v*)(eb);
        eb += 512;
        c0 += a * e.x;
        c1 += a * e.y;
    }
    atomicAdd(&ctx[b * 512 + 2 * t], c0);
    atomicAdd(&ctx[b * 512 + 2 * t + 1], c1);
}

extern "C" void kernel_launch(void* const* d_in, const int* in_sizes, int n_in,
                              void* d_out, int out_size, void* d_ws, size_t ws_size,
                              hipStream_t stream) {
    const float* enc    = (const float*)d_in[0];   // [64,2048,512]
    const float* query  = (const float*)d_in[1];   // [64,256]
    const int*   length = (const int*)d_in[2];     // [64]
    const float* W1     = (const float*)d_in[3];   // [768,512]
    const float* b1     = (const float*)d_in[4];   // [512]
    const float* v      = (const float*)d_in[5];   // [512]

    float* out = (float*)d_out;
    float* ctx = out;                // [64,512]
    float* att = out + 64 * 512;     // [64,2048]

    char* ws = (char*)d_ws;
    float* part        = (float*)ws;                               // 8*M f32 = 4MB
    float* qc          = (float*)(ws + 8 * MTOT * 4);              // 128KB
    unsigned short* Wt = (unsigned short*)(ws + 8 * MTOT * 4 + 64 * 512 * 4); // 512KB

    prep_wt_kernel<<<256, 256, 0, stream>>>(W1, Wt);
    prep_qc_kernel<<<64, 256, 0, stream>>>(query, W1, b1, qc);

    gemm_logits_kernel<<<4096, 256, 0, stream>>>(enc, Wt, qc, v, length, part);

    softmax_kernel<<<64, 256, 0, stream>>>(part, length, att, ctx);

    dim3 g3(64, 16);
    ctx_kernel<<<g3, 256, 0, stream>>>(att, enc, length, ctx);
}

// Round 10
// 140.768 us; speedup vs baseline: 2.3275x; 2.3275x over previous
//
#include <hip/hip_runtime.h>

typedef __attribute__((ext_vector_type(4))) float float4v;
typedef __attribute__((ext_vector_type(2))) float float2v;
typedef __attribute__((ext_vector_type(8))) short short8;
typedef __attribute__((ext_vector_type(4))) float f32x4;

#define NEGV (-1000000000.0f)

// B=64, L=2048, E=512, Q=256; M = 131072, K = 512, N = 512
#define MTOT (64 * 2048)

__device__ __forceinline__ unsigned short f2bf(float f) {
    unsigned int u = __float_as_uint(f);
    u += 0x7fffu + ((u >> 16) & 1u);   // RNE round to bf16
    return (unsigned short)(u >> 16);
}

// async global->LDS, 16B per lane, LDS dest = wave-uniform base + lane*16
__device__ __forceinline__ void gload_lds16(const void* g, void* l) {
    __builtin_amdgcn_global_load_lds(
        (__attribute__((address_space(1))) unsigned int*)(unsigned long long)(g),
        (__attribute__((address_space(3))) unsigned int*)(unsigned int)(unsigned long long)(l),
        16, 0, 0);
}

// Wt[e][c] = bf16(W1[c][e]) via LDS 32x32 tile transpose (coalesced both sides).
__global__ __launch_bounds__(256)
void prep_wt_kernel(const float* __restrict__ W1, unsigned short* __restrict__ Wt) {
    __shared__ float t[32][33];
    int bx = blockIdx.x & 15;    // c tile
    int by = blockIdx.x >> 4;    // e tile
    int tx = threadIdx.x & 31;
    int ty = threadIdx.x >> 5;   // 0..7
    #pragma unroll
    for (int i = 0; i < 4; ++i)
        t[ty + 8 * i][tx] = W1[(bx * 32 + ty + 8 * i) * 512 + by * 32 + tx];
    __syncthreads();
    #pragma unroll
    for (int i = 0; i < 4; ++i)
        Wt[(by * 32 + ty + 8 * i) * 512 + bx * 32 + tx] = f2bf(t[tx][ty + 8 * i]);
}

// qc[b][e] = b1[e] + sum_q query[b][q] * W1[512+q][e]
__global__ void prep_qc_kernel(const float* __restrict__ query, const float* __restrict__ W1,
                               const float* __restrict__ b1, float* __restrict__ qc) {
    int b = blockIdx.x;
    int e = threadIdx.x;           // 256 threads -> cols e and e+256
    float acc0 = b1[e];
    float acc1 = b1[e + 256];
    const float* w = W1 + 512 * 512;
    #pragma unroll 8
    for (int q = 0; q < 256; ++q) {
        float qv = query[b * 256 + q];
        acc0 += qv * w[q * 512 + e];
        acc1 += qv * w[q * 512 + e + 256];
    }
    qc[b * 512 + e] = acc0;
    qc[b * 512 + e + 256] = acc1;
}

// BM=128 x BN=512 (full N) per block, BK=32, 16 waves (1024 thr).
// A read EXACTLY ONCE (reg-staged f32 -> plain-C f2bf -> swizzled ds_write,
// 16B/thread); B (32KB/step) via global_load_lds, dbuf-2, R7's proven KITER
// (vmcnt(2) -> cvt -> drain -> barrier). Wave tile 64x64: 16 MFMA/step.
// Logits complete in-block via LDS reduce over the 8 wn waves.
__global__ __launch_bounds__(1024)
void gemm_logits_kernel(const float* __restrict__ A,            // encoded [M][512] f32
                        const unsigned short* __restrict__ Wt,  // [512 n][512 k] bf16
                        const float* __restrict__ qc,           // [64][512]
                        const float* __restrict__ v,            // [512]
                        const int* __restrict__ length,         // [64]
                        float* __restrict__ logits)             // [M]
{
    int bm = blockIdx.x;           // 0..1023 row tile (natural XCD round-robin)
    int b = bm >> 4;
    int l0 = (bm & 15) * 128;
    if (l0 >= length[b]) return;   // fully-masked tile

    __shared__ unsigned short As[2][128 * 32];   // 2 x 8 KB, swizzled
    __shared__ unsigned short Bs[2][512 * 32];   // 2 x 32 KB, swizzled
    __shared__ float lred[128][8];

    int tid = threadIdx.x;
    int lane = tid & 63;
    int w = tid >> 6;              // 0..15
    int wm = w >> 3, wn = w & 7;   // 2 x 8 wave grid; wave tile 64x64
    long row0 = (long)bm * 128;

    // --- A reg-staging: thread -> row r = tid>>3, k-eighth e8 = tid&7 (16B) ---
    int ar_r = tid >> 3;
    int ar_e = tid & 7;
    const char* gAr = (const char*)A + (row0 + ar_r) * 2048 + ar_e * 16;
    int awr = ar_r * 64 + ((ar_e * 8) ^ (((ar_r >> 1) & 3) << 4));

    // --- B staging: linear LDS dest (wave base + lane*16), pre-swizzled src ---
    int offw = w * 2048 + lane * 16;             // this wave's 2KB of 32KB slot
    const char* gB0;
    const char* gB1;
    {
        int o = offw;
        int r = o >> 6;
        gB0 = (const char*)Wt + r * 1024 + ((o & 63) ^ (((r >> 1) & 3) << 4));
        o = offw + 1024;
        r = o >> 6;
        gB1 = (const char*)Wt + r * 1024 + ((o & 63) ^ (((r >> 1) & 3) << 4));
    }

    // --- fragment read byte offsets (within one slot) ---
    int aoff[4], boff[4];
    int kb = 16 * (lane >> 4);
    #pragma unroll
    for (int mi = 0; mi < 4; ++mi) {
        int ar = wm * 64 + (lane & 15) + mi * 16;
        aoff[mi] = ar * 64 + (kb ^ (((ar >> 1) & 3) << 4));
    }
    #pragma unroll
    for (int ni = 0; ni < 4; ++ni) {
        int br = wn * 64 + (lane & 15) + ni * 16;
        boff[ni] = br * 64 + (kb ^ (((br >> 1) & 3) << 4));
    }

    f32x4 acc[4][4] = {};
    float4v P;

#define GISSUE(t, sI) do {                                                   \
    P = *(const float4v*)(gAr + (t) * 128);                                  \
    char* lb_ = (char*)(&Bs[0][0]) + (sI) * 32768 + offw;                    \
    gload_lds16(gB0 + (t) * 64, lb_);                                        \
    gload_lds16(gB1 + (t) * 64, lb_ + 1024);                                 \
} while (0)

#define CVTW(sW) do {                                                        \
    union { unsigned int u[2]; unsigned long long ll; } pk_;                 \
    pk_.u[0] = (unsigned int)f2bf(P[0]) | ((unsigned int)f2bf(P[1]) << 16);  \
    pk_.u[1] = (unsigned int)f2bf(P[2]) | ((unsigned int)f2bf(P[3]) << 16);  \
    *(unsigned long long*)((char*)(&As[0][0]) + (sW) * 8192 + awr) = pk_.ll; \
} while (0)

#define KCOMP(sC) do {                                                       \
    const char* as_ = (const char*)(&As[0][0]) + (sC) * 8192;                \
    const char* bs_ = (const char*)(&Bs[0][0]) + (sC) * 32768;               \
    short8 af_[4];                                                           \
    _Pragma("unroll")                                                        \
    for (int mi = 0; mi < 4; ++mi) af_[mi] = *(const short8*)(as_ + aoff[mi]); \
    _Pragma("unroll")                                                        \
    for (int ni = 0; ni < 4; ++ni) {                                         \
        short8 bf_ = *(const short8*)(bs_ + boff[ni]);                       \
        _Pragma("unroll")                                                    \
        for (int mi = 0; mi < 4; ++mi)                                       \
            acc[mi][ni] = __builtin_amdgcn_mfma_f32_16x16x32_bf16(af_[mi], bf_, acc[mi][ni], 0, 0, 0); \
    }                                                                        \
} while (0)

#define KITER(t) do {                                                        \
    GISSUE((t) + 1, ((t) + 1) & 1);                                          \
    KCOMP((t) & 1);                                                          \
    asm volatile("s_waitcnt vmcnt(2)" ::: "memory");                         \
    CVTW(((t) + 1) & 1);                                                     \
    asm volatile("s_waitcnt vmcnt(0) lgkmcnt(0)" ::: "memory");              \
    __builtin_amdgcn_s_barrier();                                            \
    asm volatile("" ::: "memory");                                           \
} while (0)

    // prologue: stage K-step 0 into slot 0
    GISSUE(0, 0);
    asm volatile("s_waitcnt vmcnt(2)" ::: "memory");   // A regs landed
    CVTW(0);
    asm volatile("s_waitcnt vmcnt(0) lgkmcnt(0)" ::: "memory");
    __builtin_amdgcn_s_barrier();
    asm volatile("" ::: "memory");

    KITER(0);  KITER(1);  KITER(2);  KITER(3);
    KITER(4);  KITER(5);  KITER(6);  KITER(7);
    KITER(8);  KITER(9);  KITER(10); KITER(11);
    KITER(12); KITER(13); KITER(14);
    KCOMP(1);                                          // t = 15

    // epilogue: u = tanh(acc + qc), per-wave 64-col partial via 16-lane
    // reduce, then in-block reduce over the 8 wn waves in LDS.
    const float* qcb = qc + b * 512;
    float vcol[4], qcol[4];
    #pragma unroll
    for (int ni = 0; ni < 4; ++ni) {
        int c = wn * 64 + ni * 16 + (lane & 15);
        vcol[ni] = v[c];
        qcol[ni] = qcb[c];
    }
    #pragma unroll
    for (int mi = 0; mi < 4; ++mi) {
        #pragma unroll
        for (int j2 = 0; j2 < 4; ++j2) {
            float s = 0.f;
            #pragma unroll
            for (int ni = 0; ni < 4; ++ni) {
                float xx = acc[mi][ni][j2] + qcol[ni];
                float e2 = __expf(2.0f * xx);
                float tt = 1.0f - 2.0f * __builtin_amdgcn_rcpf(e2 + 1.0f);
                s += tt * vcol[ni];
            }
            s += __shfl_xor(s, 1);
            s += __shfl_xor(s, 2);
            s += __shfl_xor(s, 4);
            s += __shfl_xor(s, 8);
            if ((lane & 15) == 0)
                lred[wm * 64 + mi * 16 + 4 * (lane >> 4) + j2][wn] = s;
        }
    }
    __syncthreads();
    if (tid < 128) {
        float lg = 0.f;
        #pragma unroll
        for (int q = 0; q < 8; ++q) lg += lred[tid][q];
        logits[row0 + tid] = lg;
    }
}

// masked softmax per batch row; also zeroes ctx[b]
__global__ void softmax_kernel(const float* __restrict__ logits, const int* __restrict__ length,
                               float* __restrict__ att, float* __restrict__ ctx) {
    int b = blockIdx.x;
    int len = length[b];
    int tid = threadIdx.x;     // 256
    int lane = tid & 63, wv = tid >> 6;
    const float* p0 = logits + b * 2048;
    float* ab = att + b * 2048;

    ctx[b * 512 + tid] = 0.f;              // zero context (ctx_kernel atomicAdds)
    ctx[b * 512 + 256 + tid] = 0.f;

    float vals[8];
    float mymax = -3.402823466e38f;
    #pragma unroll
    for (int i = 0; i < 8; ++i) {
        int l = tid + i * 256;
        float xv = (l < len) ? p0[l] : NEGV;
        vals[i] = xv;
        mymax = fmaxf(mymax, xv);
    }
    #pragma unroll
    for (int m = 32; m; m >>= 1) mymax = fmaxf(mymax, __shfl_xor(mymax, m));
    __shared__ float sm[4];
    if (lane == 0) sm[wv] = mymax;
    __syncthreads();
    float bmax = fmaxf(fmaxf(sm[0], sm[1]), fmaxf(sm[2], sm[3]));

    float mysum = 0.f;
    #pragma unroll
    for (int i = 0; i < 8; ++i) {
        int l = tid + i * 256;
        float e = (l < len) ? __expf(vals[i] - bmax) : 0.f;
        vals[i] = e;
        mysum += e;
    }
    #pragma unroll
    for (int m = 32; m; m >>= 1) mysum += __shfl_xor(mysum, m);
    __shared__ float ss[4];
    if (lane == 0) ss[wv] = mysum;
    __syncthreads();
    float tot = ss[0] + ss[1] + ss[2] + ss[3];
    float inv = 1.0f / (tot + 1e-5f);
    #pragma unroll
    for (int i = 0; i < 8; ++i) {
        int l = tid + i * 256;
        ab[l] = vals[i] * inv;
    }
}

// context[b][e] = sum_l att[b][l] * enc[b][l][e]; skip masked L-chunks
__global__ void ctx_kernel(const float* __restrict__ att, const float* __restrict__ enc,
                           const int* __restrict__ length, float* __restrict__ ctx) {
    int b = blockIdx.x;        // 64
    int lc = blockIdx.y;       // 16 chunks of 128
    int len = length[b];
    int l0 = lc * 128;
    if (l0 >= len) return;
    int lim = len - l0;
    if (lim > 128) lim = 128;

    int t = threadIdx.x;       // 256 -> 2 cols each
    const float* ab = att + b * 2048 + l0;
    const float* eb = enc + ((long)(b * 2048 + l0)) * 512 + t * 2;
    float c0 = 0.f, c1 = 0.f;
    #pragma unroll 4
    for (int l = 0; l < lim; ++l) {
        float a = ab[l];
        float2v e = *(const float2v*)(eb);
        eb += 512;
        c0 += a * e.x;
        c1 += a * e.y;
    }
    atomicAdd(&ctx[b * 512 + 2 * t], c0);
    atomicAdd(&ctx[b * 512 + 2 * t + 1], c1);
}

extern "C" void kernel_launch(void* const* d_in, const int* in_sizes, int n_in,
                              void* d_out, int out_size, void* d_ws, size_t ws_size,
                              hipStream_t stream) {
    const float* enc    = (const float*)d_in[0];   // [64,2048,512]
    const float* query  = (const float*)d_in[1];   // [64,256]
    const int*   length = (const int*)d_in[2];     // [64]
    const float* W1     = (const float*)d_in[3];   // [768,512]
    const float* b1     = (const float*)d_in[4];   // [512]
    const float* v      = (const float*)d_in[5];   // [512]

    float* out = (float*)d_out;
    float* ctx = out;                // [64,512]
    float* att = out + 64 * 512;     // [64,2048]

    char* ws = (char*)d_ws;
    float* logits      = (float*)ws;                               // M f32 = 512KB
    float* qc          = (float*)(ws + MTOT * 4);                  // 128KB
    unsigned short* Wt = (unsigned short*)(ws + MTOT * 4 + 64 * 512 * 4); // 512KB

    prep_wt_kernel<<<256, 256, 0, stream>>>(W1, Wt);
    prep_qc_kernel<<<64, 256, 0, stream>>>(query, W1, b1, qc);

    gemm_logits_kernel<<<1024, 1024, 0, stream>>>(enc, Wt, qc, v, length, logits);

    softmax_kernel<<<64, 256, 0, stream>>>(logits, length, att, ctx);

    dim3 g3(64, 16);
    ctx_kernel<<<g3, 256, 0, stream>>>(att, enc, length, ctx);
}